// Round 5
// baseline (540.366 us; speedup 1.0000x reference)
//
#include <hip/hip_runtime.h>
#include <stdint.h>
#include <stddef.h>

// Problem constants (reference: NB=4, B=16, C=256, L=4096)
#define NBR 4
#define BSZ 16
#define CHN 256
#define LEN 4096
#define NB_B 64            // NBR*BSZ
#define BL   65536         // BSZ*LEN
#define BN_EPS 1e-5f
#define W_EL (NBR*CHN*CHN) // 262144 elements per weight tensor

typedef unsigned short ushortT;
typedef unsigned short ushort4_t __attribute__((ext_vector_type(4)));
typedef unsigned short ushort8_t __attribute__((ext_vector_type(8)));
typedef short bf16x8 __attribute__((ext_vector_type(8)));
typedef float f32x4 __attribute__((ext_vector_type(4)));

__device__ __forceinline__ float bf2f(ushortT u) {
    return __uint_as_float(((unsigned)u) << 16);
}
__device__ __forceinline__ ushortT f2bf(float f) {
    unsigned b = __float_as_uint(f);
    return (ushortT)((b + 0x7FFFu + ((b >> 16) & 1u)) >> 16);
}
// order-preserving float->uint encoding (monotone); memset-0 init is below enc(-inf)
__device__ __forceinline__ unsigned encf(float f) {
    unsigned b = __float_as_uint(f);
    return (b & 0x80000000u) ? ~b : (b | 0x80000000u);
}
__device__ __forceinline__ float decf(unsigned u) {
    unsigned b = (u & 0x80000000u) ? (u ^ 0x80000000u) : ~u;
    return __uint_as_float(b);
}

// LDS swizzles (byte offsets). sX rows are 512B (256 c bf16), sW rows 128B (64 c bf16).
__device__ __forceinline__ int swzX(int row, int cb) {
    return row * 512 + (cb ^ ((row & 7) << 4) ^ (((row >> 3) & 3) << 7));
}
__device__ __forceinline__ int swzW(int row, int cb) {
    return row * 128 + (cb ^ ((row & 7) << 4));
}

// T14 async-STAGE split for W chunk [o=128][c=64] (bf16 source):
// issue-early global->reg, write-late reg->LDS (swizzled).
__device__ __forceinline__ void stage_w_load(const ushortT* Wb, int obase, int kb, int tid,
                                             ushort8_t wreg[4])
{
    const int r = tid >> 1;
    const int h = tid & 1;
    const ushortT* wp = Wb + (size_t)(obase + r) * CHN + kb + h * 32;
#pragma unroll
    for (int i = 0; i < 4; ++i) wreg[i] = *(const ushort8_t*)(wp + i * 8);
}
__device__ __forceinline__ void stage_w_write(ushortT* sW, int tid, const ushort8_t wreg[4])
{
    const int r = tid >> 1;
    const int h = tid & 1;
#pragma unroll
    for (int i = 0; i < 4; ++i)
        *(ushort8_t*)((char*)sW + swzW(r, h * 64 + i * 16)) = wreg[i];
}

// One K-chunk (64) of MFMA.
// SWAP=false: A = x (M=l), B = W (N=o), acc[mf][nf] row=l col=o.
// SWAP=true : A = W (M=o), B = x (N=l), acc[nf][mf] row=o col=l.
// Both operand fragments are "8 contiguous k at row lane&15", so loads are identical.
template <bool SWAP>
__device__ __forceinline__ void mfma_chunk(const ushortT* sX, const ushortT* sW,
                                           f32x4 acc[4][4], int wr, int wc, int lane, int kb)
{
    const int am = wr * 64 + (lane & 15);
    const int bo = wc * 64 + (lane & 15);
    const int kg = (lane >> 4) * 16;   // byte offset of this lane's k-group
#pragma unroll
    for (int s = 0; s < 2; ++s) {
        bf16x8 a[4], b[4];
#pragma unroll
        for (int mf = 0; mf < 4; ++mf)
            a[mf] = *(const bf16x8*)((const char*)sX + swzX(am + mf * 16, kb * 2 + s * 64 + kg));
#pragma unroll
        for (int nf = 0; nf < 4; ++nf)
            b[nf] = *(const bf16x8*)((const char*)sW + swzW(bo + nf * 16, s * 64 + kg));
#pragma unroll
        for (int mf = 0; mf < 4; ++mf)
#pragma unroll
            for (int nf = 0; nf < 4; ++nf) {
                if (!SWAP)
                    acc[mf][nf] = __builtin_amdgcn_mfma_f32_16x16x32_bf16(a[mf], b[nf], acc[mf][nf], 0, 0, 0);
                else
                    acc[nf][mf] = __builtin_amdgcn_mfma_f32_16x16x32_bf16(b[nf], a[mf], acc[nf][mf], 0, 0, 0);
            }
    }
}

// ---------------------------------------------------------------------------
// QKV fused: coalesced float4 x-load + in-LDS chunked transpose -> sX (bf16),
// then 6 GEMM-tiles (Wq,Wk,Wv x 2 o-halves) with W-prefetch pipeline.
// Wq/Wk epilogue: per-o sum & max over l -> atomics.
// Wv epilogue: swapped-operand GEMM so acc spans o -> packed vT[z][l][c] store.
// ---------------------------------------------------------------------------
__global__ __launch_bounds__(256, 2)
void qkv_kernel(const float* __restrict__ x, const ushortT* __restrict__ Wbf,
                const float* __restrict__ bv,
                float* __restrict__ qsum, unsigned* __restrict__ qmax,
                float* __restrict__ ksum, unsigned* __restrict__ kmax,
                ushortT* __restrict__ vT)
{
    __shared__ ushortT sX[128 * 256];   // 64 KiB
    __shared__ ushortT sW[128 * 64];    // 16 KiB (also fp32 bounce buffer)
    const int tid = threadIdx.x;
    const int lane = tid & 63;
    const int wv = tid >> 6;
    const int wr = wv >> 1, wc = wv & 1;
    const int lbase = blockIdx.x * 128;
    const int z = blockIdx.y;
    const int n = z >> 4;

    ushort8_t wreg[4];
    stage_w_load(Wbf + (size_t)n * CHN * CHN, 0, 0, tid, wreg);   // w=0, ot=0, kb=0

    // ---- x staging: coalesced float4 loads, transpose via LDS bounce ----
    {
        float* raw = (float*)sW;            // [32 c][128 l] fp32 = 16 KiB
        const int tq = tid >> 5;            // c sub-row 0..7
        const int tl = tid & 31;            // float4 column 0..31
        const int l  = tid & 127;
        const int h  = tid >> 7;
        const float* xz = x + (size_t)z * CHN * LEN + lbase;
        float4 v4[4];
#pragma unroll
        for (int q = 0; q < 4; ++q)
            v4[q] = *(const float4*)(xz + (size_t)(q * 8 + tq) * LEN + tl * 4);
        for (int cc = 0; cc < 8; ++cc) {
            __syncthreads();                 // raw region free
#pragma unroll
            for (int q = 0; q < 4; ++q)
                *(float4*)(raw + (q * 8 + tq) * 128 + tl * 4) = v4[q];
            if (cc < 7) {
#pragma unroll
                for (int q = 0; q < 4; ++q)
                    v4[q] = *(const float4*)(xz + (size_t)((cc + 1) * 32 + q * 8 + tq) * LEN + tl * 4);
            }
            __syncthreads();                 // raw ready
#pragma unroll
            for (int p = 0; p < 2; ++p) {
                int oct = h * 2 + p;
                ushort8_t u8;
#pragma unroll
                for (int i = 0; i < 8; ++i) u8[i] = f2bf(raw[(oct * 8 + i) * 128 + l]);
                *(ushort8_t*)((char*)sX + swzX(l, (cc * 32 + oct * 8) * 2)) = u8;
            }
        }
    }

    for (int w = 0; w < 3; ++w) {
        for (int ot = 0; ot < 2; ++ot) {
            const int obase = ot * 128;
            f32x4 acc[4][4];
            const f32x4 z4 = {0.f, 0.f, 0.f, 0.f};
#pragma unroll
            for (int mf = 0; mf < 4; ++mf)
#pragma unroll
                for (int nf = 0; nf < 4; ++nf) acc[mf][nf] = z4;

#pragma unroll
            for (int kb = 0; kb < 4; ++kb) {
                __syncthreads();                       // prev phase done with sW
                stage_w_write(sW, tid, wreg);
                int cidx = (w * 2 + ot) * 4 + kb + 1;  // next chunk 1..24
                if (cidx < 24) {
                    int nw = cidx >> 3, not_ = (cidx >> 2) & 1, nkb = cidx & 3;
                    stage_w_load(Wbf + ((size_t)nw * NBR + n) * CHN * CHN,
                                 not_ * 128, nkb * 64, tid, wreg);
                }
                __syncthreads();                       // sW ready
                if (w < 2) mfma_chunk<false>(sX, sW, acc, wr, wc, lane, kb * 64);
                else       mfma_chunk<true >(sX, sW, acc, wr, wc, lane, kb * 64);
            }

            if (w < 2) {
                // acc[mf][nf]: row=l, col=o
                float* rs = (w == 0) ? qsum : ksum;
                unsigned* rm = (w == 0) ? qmax : kmax;
#pragma unroll
                for (int nf = 0; nf < 4; ++nf) {
                    float s = 0.f, m = -3.4e38f;
#pragma unroll
                    for (int mf = 0; mf < 4; ++mf)
#pragma unroll
                        for (int r = 0; r < 4; ++r) {
                            float v = acc[mf][nf][r];
                            s += v; m = fmaxf(m, v);
                        }
                    s += __shfl_xor(s, 16); s += __shfl_xor(s, 32);
                    m = fmaxf(m, __shfl_xor(m, 16)); m = fmaxf(m, __shfl_xor(m, 32));
                    if (lane < 16) {
                        int o = obase + wc * 64 + nf * 16 + lane;
                        atomicAdd(&rs[z * CHN + o], s);
                        atomicMax(&rm[z * CHN + o], encf(m));
                    }
                }
            } else {
                // acc[nf][mf]: row=o (spanned by regs), col=l -> packed vT store
#pragma unroll
                for (int nf = 0; nf < 4; ++nf) {
                    int o0 = obase + wc * 64 + nf * 16 + ((lane >> 4) << 2);
                    float b4[4];
#pragma unroll
                    for (int r = 0; r < 4; ++r) b4[r] = bv[n * CHN + o0 + r];
#pragma unroll
                    for (int mf = 0; mf < 4; ++mf) {
                        int l = lbase + wr * 64 + mf * 16 + (lane & 15);
                        ushort4_t u;
#pragma unroll
                        for (int r = 0; r < 4; ++r) u[r] = f2bf(acc[nf][mf][r] + b4[r]);
                        *(ushort4_t*)(vT + ((size_t)z * LEN + l) * CHN + o0) = u;
                    }
                }
            }
        }
    }
}

// ---------------------------------------------------------------------------
// O GEMM with fused aggregation: agg[i,b,:,l] = sum_j attn[i,j,b] * v[j,b,:,l]
// read directly from vT[z][l][c] (coalesced), combined in-reg -> sX.
// Then Wo GEMM -> out_pre[z][c][l] (bf16) + BN partial stats.
// ---------------------------------------------------------------------------
__global__ __launch_bounds__(256, 2)
void ogemm_kernel(const ushortT* __restrict__ vT, const ushortT* __restrict__ Wbo,
                  const float* __restrict__ attn, const float* __restrict__ bo_,
                  float* __restrict__ bnsum, float* __restrict__ bnss,
                  ushortT* __restrict__ outpre)
{
    __shared__ ushortT sX[128 * 256];
    __shared__ ushortT sW[128 * 64];
    const int tid = threadIdx.x;
    const int lane = tid & 63;
    const int wv = tid >> 6;
    const int wr = wv >> 1, wc = wv & 1;
    const int lbase = blockIdx.x * 128;
    const int z = blockIdx.y;
    const int n = z >> 4;          // output branch i
    const int b_ = z & 15;
    const ushortT* Wb = Wbo + (size_t)n * CHN * CHN;

    ushort8_t wreg[4];
    stage_w_load(Wb, 0, 0, tid, wreg);

    float aj[4];
#pragma unroll
    for (int j = 0; j < 4; ++j) aj[j] = attn[(n * 4 + j) * BSZ + b_];

    // ---- stage agg tile: 4x coalesced vT reads + weighted combine -> sX ----
#pragma unroll 4
    for (int u = 0; u < 16; ++u) {
        int g = u * 256 + tid;
        int l = g >> 5;                  // 0..127
        int cg = g & 31;                 // ushort8 group along c
        size_t boff = ((size_t)lbase + l) * CHN + cg * 8;
        float acc8[8];
#pragma unroll
        for (int e = 0; e < 8; ++e) acc8[e] = 0.f;
#pragma unroll
        for (int j = 0; j < 4; ++j) {
            ushort8_t r8 = *(const ushort8_t*)(vT + (size_t)(j * BSZ + b_) * LEN * CHN + boff);
#pragma unroll
            for (int e = 0; e < 8; ++e) acc8[e] += aj[j] * bf2f(r8[e]);
        }
        ushort8_t o8;
#pragma unroll
        for (int e = 0; e < 8; ++e) o8[e] = f2bf(acc8[e]);
        *(ushort8_t*)((char*)sX + swzX(l, cg * 16)) = o8;
    }

    for (int ot = 0; ot < 2; ++ot) {
        const int obase = ot * 128;
        f32x4 acc[4][4];
        const f32x4 z4 = {0.f, 0.f, 0.f, 0.f};
#pragma unroll
        for (int mf = 0; mf < 4; ++mf)
#pragma unroll
            for (int nf = 0; nf < 4; ++nf) acc[mf][nf] = z4;

#pragma unroll
        for (int kb = 0; kb < 4; ++kb) {
            __syncthreads();
            stage_w_write(sW, tid, wreg);
            int cidx = ot * 4 + kb + 1;   // next chunk 1..8
            if (cidx < 8) {
                int not_ = (cidx >> 2) & 1, nkb = cidx & 3;
                stage_w_load(Wb, not_ * 128, nkb * 64, tid, wreg);
            }
            __syncthreads();
            mfma_chunk<false>(sX, sW, acc, wr, wc, lane, kb * 64);
        }

#pragma unroll
        for (int nf = 0; nf < 4; ++nf) {
            int o = obase + wc * 64 + nf * 16 + (lane & 15);
            float bb = bo_[n * CHN + o];
            float s = 0.f, q2 = 0.f;
#pragma unroll
            for (int mf = 0; mf < 4; ++mf) {
                int l = lbase + wr * 64 + mf * 16 + ((lane >> 4) << 2);
                ushort4_t u;
#pragma unroll
                for (int r = 0; r < 4; ++r) {
                    float v = acc[mf][nf][r] + bb;
                    u[r] = f2bf(v);
                    s += v; q2 += v * v;
                }
                *(ushort4_t*)(outpre + (size_t)(z * CHN + o) * LEN + l) = u;
            }
            s += __shfl_xor(s, 16); s += __shfl_xor(s, 32);
            q2 += __shfl_xor(q2, 16); q2 += __shfl_xor(q2, 32);
            if (lane < 16) {
                atomicAdd(&bnsum[n * CHN + o], s);
                atomicAdd(&bnss[n * CHN + o], q2);
            }
        }
    }
}

// convert all 4 weight tensors fp32 -> bf16 into Wbf [w][n][o][c]
__global__ void wcvt_kernel(const float* __restrict__ Wq, const float* __restrict__ Wk,
                            const float* __restrict__ Wv, const float* __restrict__ Wo,
                            ushortT* __restrict__ Wbf)
{
    int t = blockIdx.x * 256 + threadIdx.x;    // float4 units
    const int per = W_EL / 4;                  // 65536
    if (t < 4 * per) {
        const float* srcs[4] = {Wq, Wk, Wv, Wo};
        int w = t / per;
        int r = t - w * per;
        float4 f = *(const float4*)(srcs[w] + (size_t)r * 4);
        ushort4_t u = {f2bf(f.x), f2bf(f.y), f2bf(f.z), f2bf(f.w)};
        *(ushort4_t*)(Wbf + (size_t)w * W_EL + (size_t)r * 4) = u;
    }
}

// ---------------------------------------------------------------------------
// attention coefficients: scores[i,j,b] = (sum_c sq*sk) * edge_w[i,j] / 64
// attn[i,j,b] = softmax_j(scores) * softmax(branch_imp)[j]
// sq = qsum/L + dec(qmax) + 2*bq  (mean+max, bias shifts both by bq)
// ---------------------------------------------------------------------------
__global__ void attn_kernel(const float* __restrict__ qsum, const unsigned* __restrict__ qmax,
                            const float* __restrict__ ksum, const unsigned* __restrict__ kmax,
                            const float* __restrict__ bq, const float* __restrict__ bk,
                            const float* __restrict__ edge, const float* __restrict__ bimp,
                            float* __restrict__ attn)
{
    __shared__ float sc[NBR][NBR][BSZ];
    int tid = threadIdx.x;           // 256 threads == 4*4*16
    int i = tid >> 6, j = (tid >> 4) & 3, b = tid & 15;
    float s = 0.f;
    const float invL = 1.0f / (float)LEN;
    for (int c = 0; c < CHN; ++c) {
        int qi = (i * BSZ + b) * CHN + c;
        int ki = (j * BSZ + b) * CHN + c;
        float sq = qsum[qi] * invL + decf(qmax[qi]) + 2.f * bq[i * CHN + c];
        float sk = ksum[ki] * invL + decf(kmax[ki]) + 2.f * bk[j * CHN + c];
        s += sq * sk;
    }
    sc[i][j][b] = s * edge[i * 4 + j] * (1.0f / 64.0f);
    __syncthreads();
    if (tid < 64) {
        int ii = tid >> 4, bb = tid & 15;
        float m = -3.4e38f;
        for (int jj = 0; jj < 4; ++jj) m = fmaxf(m, sc[ii][jj][bb]);
        float e[4]; float sum = 0.f;
        for (int jj = 0; jj < 4; ++jj) { e[jj] = __expf(sc[ii][jj][bb] - m); sum += e[jj]; }
        float bm = fmaxf(fmaxf(bimp[0], bimp[1]), fmaxf(bimp[2], bimp[3]));
        float be[4]; float bs = 0.f;
        for (int jj = 0; jj < 4; ++jj) { be[jj] = __expf(bimp[jj] - bm); bs += be[jj]; }
        for (int jj = 0; jj < 4; ++jj)
            attn[(ii * 4 + jj) * BSZ + bb] = (e[jj] / sum) * (be[jj] / bs);
    }
}

// finalize BN affine: scale = gamma*rsqrt(var+eps), shift = beta - mean*scale
__global__ void bnfin_kernel(const float* __restrict__ bnsum, const float* __restrict__ bnss,
                             const float* __restrict__ gamma, const float* __restrict__ beta,
                             float* __restrict__ scl, float* __restrict__ shf)
{
    int t = blockIdx.x * blockDim.x + threadIdx.x;   // 0..1023 = n*256+c
    if (t < NBR * CHN) {
        const float inv = 1.0f / (float)BL;
        float mean = bnsum[t] * inv;
        float var = bnss[t] * inv - mean * mean;
        float rs = rsqrtf(var + BN_EPS);
        float s = gamma[t] * rs;
        scl[t] = s;
        shf[t] = beta[t] - mean * s;
    }
}

// out = relu(out_pre*scale + shift) + x
__global__ __launch_bounds__(256)
void final_kernel(const ushortT* __restrict__ outpre, const float* __restrict__ x,
                  const float* __restrict__ scl, const float* __restrict__ shf,
                  float* __restrict__ out)
{
    const long long U = (long long)NB_B * CHN * (LEN / 8);   // 8,388,608 units of 8
    for (long long u = (long long)blockIdx.x * blockDim.x + threadIdx.x; u < U;
         u += (long long)gridDim.x * blockDim.x) {
        int l0 = (int)(u & 511) * 8;
        int c  = (int)(u >> 9) & 255;
        int zz = (int)(u >> 17);          // n*16+b
        int n  = zz >> 4;
        size_t base = ((size_t)zz * CHN + c) * LEN + l0;
        ushort8_t op = *(const ushort8_t*)(outpre + base);
        float4 x0 = *(const float4*)(x + base);
        float4 x1 = *(const float4*)(x + base + 4);
        float sc = scl[n * CHN + c];
        float sh = shf[n * CHN + c];
        float xr[8] = {x0.x, x0.y, x0.z, x0.w, x1.x, x1.y, x1.z, x1.w};
        float res[8];
#pragma unroll
        for (int e = 0; e < 8; ++e) {
            float bn = bf2f(op[e]) * sc + sh;
            res[e] = fmaxf(bn, 0.f) + xr[e];
        }
        float4 o0 = {res[0], res[1], res[2], res[3]};
        float4 o1 = {res[4], res[5], res[6], res[7]};
        *(float4*)(out + base) = o0;
        *(float4*)(out + base + 4) = o1;
    }
}

extern "C" void kernel_launch(void* const* d_in, const int* in_sizes, int n_in,
                              void* d_out, int out_size, void* d_ws, size_t ws_size,
                              hipStream_t stream)
{
    const float* x     = (const float*)d_in[0];
    const float* Wq    = (const float*)d_in[1];
    const float* bq    = (const float*)d_in[2];
    const float* Wk    = (const float*)d_in[3];
    const float* bk    = (const float*)d_in[4];
    const float* Wv    = (const float*)d_in[5];
    const float* bv    = (const float*)d_in[6];
    const float* Wo    = (const float*)d_in[7];
    const float* bo    = (const float*)d_in[8];
    const float* gamma = (const float*)d_in[9];
    const float* beta  = (const float*)d_in[10];
    const float* edge  = (const float*)d_in[11];
    const float* bimp  = (const float*)d_in[12];

    char* ws = (char*)d_ws;
    const size_t P_BYTES = (size_t)NBR * BSZ * CHN * LEN * 2;   // 128 MiB (bf16)
    ushortT* outpre = (ushortT*)ws;          // out_pre staging (ws)
    size_t off = P_BYTES;
    float*    qsum = (float*)(ws + off);    off += 65536;
    unsigned* qmax = (unsigned*)(ws + off); off += 65536;
    float*    ksum = (float*)(ws + off);    off += 65536;
    unsigned* kmax = (unsigned*)(ws + off); off += 65536;
    float*    attn = (float*)(ws + off);    off += 1024;
    float*    bnsum= (float*)(ws + off);    off += 4096;
    float*    bnss = (float*)(ws + off);    off += 4096;
    float*    scl  = (float*)(ws + off);    off += 4096;
    float*    shf  = (float*)(ws + off);    off += 4096;

    // zero the small accumulators (sum=0; max uses encoding where 0 < enc(-inf))
    hipMemsetAsync(ws + P_BYTES, 0, off - P_BYTES, stream);

    // d_out scratch usage (dead by the time final_kernel rewrites d_out):
    //   [0, 128Mi):   vT  (bf16, [z][l][c]) written by qkv, read by ogemm
    //   [128Mi, +2Mi): Wbf (bf16 weights)   written by wcvt
    ushortT* vT  = (ushortT*)d_out;
    ushortT* Wbf = (ushortT*)((char*)d_out + ((size_t)134217728));
    float*   outf = (float*)d_out;

    wcvt_kernel<<<(4 * W_EL / 4 + 255) / 256, 256, 0, stream>>>(Wq, Wk, Wv, Wo, Wbf);

    dim3 gq(LEN / 128, NB_B);   // (32, 64)
    qkv_kernel<<<gq, 256, 0, stream>>>(x, Wbf, bv, qsum, qmax, ksum, kmax, vT);
    attn_kernel<<<1, 256, 0, stream>>>(qsum, qmax, ksum, kmax, bq, bk, edge, bimp, attn);
    ogemm_kernel<<<gq, 256, 0, stream>>>(vT, Wbf + (size_t)3 * W_EL, attn, bo, bnsum, bnss, outpre);
    bnfin_kernel<<<4, 256, 0, stream>>>(bnsum, bnss, gamma, beta, scl, shf);
    final_kernel<<<8192, 256, 0, stream>>>(outpre, x, scl, shf, outf);
}